// Round 2
// baseline (1059.849 us; speedup 1.0000x reference)
//
#include <hip/hip_runtime.h>

// NearestNbrNegSampler: B=2048, D=256
// n[i][j][k]   = y[i][k] + (j==k ? 1 : 0) - (j-D==k ? 1 : 0),  j in [0,2D)
// nmsk[i][j]   = all_k( l[i][k] <= n[i][j][k] <= u[i][k] )
// Outputs concatenated flat: n (B*2D*D floats) then nmsk (B*2D floats 0/1).
//
// Write-bound: 1.078 GB stores vs ~6 MB reads. Floor at 6.3 TB/s ≈ 175 us.
// Key structure: row j of block i differs from y[i,:] in exactly ONE element
// (k = j mod D, +1 if j<D else -1). With row mapping j = 4t + jg (jg = wave id),
// the modified float4 COMPONENT is wave-uniform (== jg) and the modified LANE
// at iteration t is (t & 63). So the inner loop is ~5 VALU + 1 nt-store.

#define BB 2048
#define DD 256

typedef float v4f __attribute__((ext_vector_type(4)));

__global__ __launch_bounds__(256) void nnns_kernel(
    const float* __restrict__ l,
    const float* __restrict__ u,
    const float* __restrict__ y,
    float* __restrict__ n_out,
    float* __restrict__ m_out)
{
    const int i   = blockIdx.x;       // batch row
    const int tid = threadIdx.x;      // 256 threads

    // ---------------- mask part: thread tid == k ----------------
    __shared__ int s_fail;
    if (tid == 0) s_fail = 0;
    __syncthreads();

    const int k = tid;
    const float yv = y[i * DD + k];
    const float lv = l[i * DD + k];
    const float uv = u[i * DD + k];
    const bool ok = (lv <= yv) && (yv <= uv);
    if (!ok) atomicAdd(&s_fail, 1);   // coalesced per-wave by compiler
    __syncthreads();
    const int fail = s_fail;

    // "all other k pass": no failures, or exactly one failure and it's me
    const bool others = (fail == 0) || (fail == 1 && !ok);
    const float yp = yv + 1.0f;
    const float ym = yv - 1.0f;
    const bool okp = (lv <= yp) && (yp <= uv);
    const bool okm = (lv <= ym) && (ym <= uv);
    m_out[(size_t)i * (2 * DD) + k]      = (others && okp) ? 1.0f : 0.0f;
    m_out[(size_t)i * (2 * DD) + DD + k] = (others && okm) ? 1.0f : 0.0f;

    // ---------------- n part: stream 512x256 tile ----------------
    // wave jg stores rows j = 4t + jg, t = 0..127; lanes cover k via float4.
    // At iteration t: the only lane whose float4 differs from y4 is lane (t&63),
    // in component jg, with sign + for t<64 (j<256) and - for t>=64.
    const int lane = tid & 63;
    const int jg   = tid >> 6;
    const int kb   = lane * 4;

    const v4f y4 = *(const v4f*)(y + i * DD + kb);
    v4f* p = (v4f*)(n_out + (size_t)i * (2 * DD) * DD) + (size_t)jg * (DD / 4) + lane;
    // advance 4 rows (= 4 * 64 v4f) per iteration

#define NLOOP(C)                                                      \
    {                                                                 \
        _Pragma("unroll 8")                                           \
        for (int t = 0; t < 64; ++t) {                                \
            v4f v = y4;                                               \
            v.C += (lane == t) ? 1.0f : 0.0f;                         \
            __builtin_nontemporal_store(v, p);                        \
            p += 4 * (DD / 4);                                        \
        }                                                             \
        _Pragma("unroll 8")                                           \
        for (int t = 0; t < 64; ++t) {                                \
            v4f v = y4;                                               \
            v.C -= (lane == t) ? 1.0f : 0.0f;                         \
            __builtin_nontemporal_store(v, p);                        \
            p += 4 * (DD / 4);                                        \
        }                                                             \
    }

    if (jg == 0)      NLOOP(x)   // wave-uniform branch: no divergence
    else if (jg == 1) NLOOP(y)
    else if (jg == 2) NLOOP(z)
    else              NLOOP(w)
#undef NLOOP
}

extern "C" void kernel_launch(void* const* d_in, const int* in_sizes, int n_in,
                              void* d_out, int out_size, void* d_ws, size_t ws_size,
                              hipStream_t stream) {
    // setup_inputs order: a(0), b(1), c(2), l(3), u(4), h(5), y(6)
    const float* l = (const float*)d_in[3];
    const float* u = (const float*)d_in[4];
    const float* y = (const float*)d_in[6];

    float* n_out = (float*)d_out;                                   // B*2D*D
    float* m_out = (float*)d_out + (size_t)BB * (2 * DD) * DD;      // B*2D

    nnns_kernel<<<dim3(BB), dim3(256), 0, stream>>>(l, u, y, n_out, m_out);
}